// Round 13
// baseline (96.099 us; speedup 1.0000x reference)
//
#include <hip/hip_runtime.h>

#define NTH 256
#define U1H_STRIDE 21504  // 8*1024 + 8*512 + 8*256 + 8*128 + 48*128

#define PHI1 0.29504296f    // e^{-1.220703125}
#define PHI2 0.0075683594f  // e^{-4.8828125}
#define GCUT 18.0f          // Gaussian support cutoff: e^-18 = 1.5e-8

// Bank swizzle — conflict-free for in-place strides; swz(i+128k)=swz(i)+128k
// so 128-aligned group regions preserve the pattern (verified r5-r12).
__device__ __forceinline__ int swz(int i) { return i ^ (((i >> 4) & 3) * 5); }

__device__ __forceinline__ float2 cmul(float2 a, float2 b) {
  return make_float2(a.x * b.x - a.y * b.y, a.x * b.y + a.y * b.x);
}

template <int W>
__device__ __forceinline__ float wsum(float v) {
#pragma unroll
  for (int off = 1; off < W; off <<= 1) v += __shfl_xor(v, off, 64);
  return v;
}

// P(idx): output frequency of storage slot idx after the DIF stage sequence.
template <int M>
__device__ __forceinline__ int prevM(int i) {
  if (M == 128)
    return ((i >> 5) & 3) | (((i >> 3) & 3) << 2) | (((i >> 1) & 3) << 4) | ((i & 1) << 6);
  else if (M == 256)
    return ((i & 3) << 6) | (((i >> 2) & 3) << 4) | (((i >> 4) & 3) << 2) | ((i >> 6) & 3);
  else if (M == 512)
    return ((i >> 7) & 3) | (((i >> 5) & 3) << 2) | (((i >> 3) & 3) << 4) |
           (((i >> 1) & 3) << 6) | ((i & 1) << 8);
  else if (M == 1024)
    return ((i >> 8) & 3) | (((i >> 6) & 3) << 2) | (((i >> 4) & 3) << 4) |
           (((i >> 2) & 3) << 6) | ((i & 3) << 8);
  else
    return ((i >> 9) & 3) | (((i >> 7) & 3) << 2) | (((i >> 5) & 3) << 4) |
           (((i >> 3) & 3) << 6) | (((i >> 1) & 3) << 8) | ((i & 1) << 10);
}

// In-place radix-4 DIF stage; twiddles in registers.
template <bool INV>
__device__ __forceinline__ void dif4(float2* A, int j, int ls, float astep) {
  const int s = 1 << ls;
  const int e = j & (s - 1);
  const int base = ((j >> ls) << (ls + 2)) | e;
  float2 w1;
  __sincosf(astep * (float)e, &w1.y, &w1.x);
  if (INV) w1.y = -w1.y;
  const float2 w2 = cmul(w1, w1);
  const float2 w3 = cmul(w2, w1);
  const float2 a0 = A[swz(base)];
  const float2 a1 = A[swz(base + s)];
  const float2 a2 = A[swz(base + 2 * s)];
  const float2 a3 = A[swz(base + 3 * s)];
  const float t0x = a0.x + a2.x, t0y = a0.y + a2.y;
  const float t1x = a0.x - a2.x, t1y = a0.y - a2.y;
  const float t2x = a1.x + a3.x, t2y = a1.y + a3.y;
  const float bdx = a1.x - a3.x, bdy = a1.y - a3.y;
  const float sgn = INV ? -1.0f : 1.0f;
  const float t3x = sgn * bdy, t3y = -sgn * bdx;
  A[swz(base)]         = make_float2(t0x + t2x, t0y + t2y);
  A[swz(base + s)]     = cmul(make_float2(t1x + t3x, t1y + t3y), w1);
  A[swz(base + 2 * s)] = cmul(make_float2(t0x - t2x, t0y - t2y), w2);
  A[swz(base + 3 * s)] = cmul(make_float2(t1x - t3x, t1y - t3y), w3);
}

// In-place radix-4 DIT stage (transpose network; forward only).
__device__ __forceinline__ void dit4(float2* A, int j, int ls, float astep) {
  const int s = 1 << ls;
  const int e = j & (s - 1);
  const int base = ((j >> ls) << (ls + 2)) | e;
  float2 w1;
  __sincosf(astep * (float)e, &w1.y, &w1.x);
  const float2 w2 = cmul(w1, w1);
  const float2 w3 = cmul(w2, w1);
  const float2 c0 = A[swz(base)];
  const float2 c1 = cmul(A[swz(base + s)], w1);
  const float2 c2 = cmul(A[swz(base + 2 * s)], w2);
  const float2 c3 = cmul(A[swz(base + 3 * s)], w3);
  const float t0x = c0.x + c2.x, t0y = c0.y + c2.y;
  const float t1x = c0.x - c2.x, t1y = c0.y - c2.y;
  const float t2x = c1.x + c3.x, t2y = c1.y + c3.y;
  const float bdx = c1.x - c3.x, bdy = c1.y - c3.y;
  const float t3x = bdy, t3y = -bdx;
  A[swz(base)]         = make_float2(t0x + t2x, t0y + t2y);
  A[swz(base + s)]     = make_float2(t1x + t3x, t1y + t3y);
  A[swz(base + 2 * s)] = make_float2(t0x - t2x, t0y - t2y);
  A[swz(base + 3 * s)] = make_float2(t1x - t3x, t1y - t3y);
}

__device__ __forceinline__ void r2pair(float2* A, int g) {
  const float2 a = A[swz(2 * g)];
  const float2 b = A[swz(2 * g + 1)];
  A[swz(2 * g)]     = make_float2(a.x + b.x, a.y + b.y);
  A[swz(2 * g + 1)] = make_float2(a.x - b.x, a.y - b.y);
}

template <int M> struct LMof { static constexpr int v =
  (M == 2048) ? 11 : (M == 1024) ? 10 : (M == 512) ? 9 : (M == 256) ? 8 : 7; };

// Block-wide in-place DIF: natural -> P-order. M in {1024, 2048}.
template <int M, bool INV>
__device__ __forceinline__ void dif_blk(float2* A) {
  constexpr int LM = LMof<M>::v;
  constexpr int NB = M / 4;
  const int tid = (int)threadIdx.x;
#pragma unroll
  for (int ls = LM - 2; ls >= (LM & 1); ls -= 2) {
    const float astep = -1.5707963267948966f / (float)(1 << ls);
    __syncthreads();
#pragma unroll
    for (int i = 0; i < NB / NTH; ++i) dif4<INV>(A, tid + NTH * i, ls, astep);
  }
  if (LM & 1) {
    __syncthreads();
#pragma unroll
    for (int i = 0; i < (M / 2) / NTH; ++i) r2pair(A, tid + NTH * i);
  }
  __syncthreads();
}

// Block-wide in-place DIT (forward): P-order -> natural.
template <int M>
__device__ __forceinline__ void dit_blk(float2* A) {
  constexpr int LM = LMof<M>::v;
  constexpr int NB = M / 4;
  const int tid = (int)threadIdx.x;
  if (LM & 1) {
    __syncthreads();
#pragma unroll
    for (int i = 0; i < (M / 2) / NTH; ++i) r2pair(A, tid + NTH * i);
  }
#pragma unroll
  for (int ls = (LM & 1); ls <= LM - 2; ls += 2) {
    const float astep = -1.5707963267948966f / (float)(1 << ls);
    __syncthreads();
#pragma unroll
    for (int i = 0; i < NB / NTH; ++i) dit4(A, tid + NTH * i, ls, astep);
  }
  __syncthreads();
}

// Lane-group FFTs, barrier-free. LANES chosen so NB/LANES == 2 (2 independent
// butterflies per lane per stage -> ILP in the LDS dependency chain).
template <int M, bool INV, int LANES>
__device__ __forceinline__ void dif_w(float2* Aw, int l) {
  constexpr int LM = LMof<M>::v;
  constexpr int NB = M / 4;
#pragma unroll
  for (int ls = LM - 2; ls >= (LM & 1); ls -= 2) {
    const float astep = -1.5707963267948966f / (float)(1 << ls);
#pragma unroll
    for (int i = 0; i < NB / LANES; ++i) dif4<INV>(Aw, l + LANES * i, ls, astep);
  }
  if (LM & 1) {
#pragma unroll
    for (int i = 0; i < (M / 2) / LANES; ++i) r2pair(Aw, l + LANES * i);
  }
}

template <int M, int LANES>
__device__ __forceinline__ void dit_w(float2* Aw, int l) {
  constexpr int LM = LMof<M>::v;
  constexpr int NB = M / 4;
  if (LM & 1) {
#pragma unroll
    for (int i = 0; i < (M / 2) / LANES; ++i) r2pair(Aw, l + LANES * i);
  }
#pragma unroll
  for (int ls = (LM & 1); ls <= LM - 2; ls += 2) {
    const float astep = -1.5707963267948966f / (float)(1 << ls);
#pragma unroll
    for (int i = 0; i < NB / LANES; ++i) dit4(Aw, l + LANES * i, ls, astep);
  }
}

// U1h layout: o=0:1024/path; o=1:512; o=2:256; o>=3:128.
__device__ __forceinline__ int u1h_off(int j1) {
  const int o = j1 >> 3;
  if (o == 0) return j1 * 1024;
  if (o == 1) return 8192 + (j1 - 8) * 512;
  if (o == 2) return 12288 + (j1 - 16) * 256;
  return 14336 + (j1 - 24) * 128;
}

// ---------------- Stage A ----------------
__global__ __launch_bounds__(NTH) void kA(const float* __restrict__ x,
                                          float2* __restrict__ xh) {
  __shared__ float2 A[2048];
  const int n = blockIdx.x, b = n / 6, c = n % 6;
  const float* xp = x + (size_t)b * (2048 * 6) + c;
#pragma unroll
  for (int i = 0; i < 8; ++i) {
    const int t = (int)threadIdx.x + NTH * i;
    A[swz(t)] = make_float2(xp[t * 6], 0.0f);
  }
  dif_blk<2048, false>(A);
#pragma unroll
  for (int i = 0; i < 8; ++i) {
    const int t = (int)threadIdx.x + NTH * i;
    xh[(size_t)n * 2048 + prevM<2048>(t)] = A[swz(t)];
  }
}

// ---------------- Stage B: block-wide (M1 = 1024) ----------------
__device__ __forceinline__ void kB_blk(float2* A, const float2* __restrict__ src,
                                       float2* __restrict__ U1h, float* __restrict__ out,
                                       int n, int b, int c, int j1) {
  constexpr int M1 = 1024;
  constexpr int F = 2;
  constexpr int NR = M1 / NTH;
  const int tid = (int)threadIdx.x;
  const float xi = 0.4f * exp2f(-0.125f * (float)j1);
  const float sig = 0.1f * xi;
  const float i2s = 1.0f / (2.0f * sig * sig);
#pragma unroll
  for (int i = 0; i < NR; ++i) {
    const int m = tid + NTH * i;
    float2 acc = make_float2(0.0f, 0.0f);
#pragma unroll
    for (int q = 0; q < F; ++q) {
      const int f = m + q * M1;
      const float fr = (float)(f < 1024 ? f : f - 2048) * (1.0f / 2048.0f);
      const float d = fr - xi;
      const float dd = d * d * i2s;
      if (dd < GCUT) {
        const float g = __expf(-dd);
        const float2 v = src[f];
        acc.x += v.x * g; acc.y += v.y * g;
      }
    }
    A[swz(m)] = acc;
  }
  dif_blk<M1, true>(A);
#pragma unroll
  for (int i = 0; i < NR; ++i) {
    const int m = tid + NTH * i;
    const float2 zv = A[swz(m)];
    A[swz(m)] = make_float2(sqrtf(zv.x * zv.x + zv.y * zv.y) * (1.0f / 2048.0f), 0.0f);
  }
  dit_blk<M1>(A);  // V natural
  float2* dst = U1h + (size_t)n * U1H_STRIDE + u1h_off(j1);
#pragma unroll
  for (int i = 0; i < NR; ++i) {
    const int m = tid + NTH * i;
    dst[m] = A[swz(m)];
  }
  const float invM = 1.0f / (float)M1;
  const float c0 = A[0].x * invM;
  const float2 U1 = A[1], U2 = A[2];
  __syncthreads();
  const float k1 = PHI1 * 2.0f * invM, k2 = PHI2 * 2.0f * invM;
  float part = 0.0f;
#pragma unroll
  for (int i = 0; i < NR; ++i) {
    const int t = tid + NTH * i;
    float sv, cv;
    __sincosf((6.283185307179586f / (float)M1) * (float)t, &sv, &cv);
    float acc = c0 + k1 * (U1.x * cv - U1.y * sv);
    const float c2 = cv * cv - sv * sv, s2 = 2.0f * sv * cv;
    acc += k2 * (U2.x * c2 - U2.y * s2);
    part += __logf(acc + 1e-6f);
  }
  part = wsum<64>(part);
  float* scr = (float*)A;
  const int lane = tid & 63, wid = tid >> 6;
  if (lane == 0) scr[wid] = part;
  __syncthreads();
  if (tid == 0)
    out[((size_t)b * 440 + j1) * 6 + c] = (scr[0] + scr[1] + scr[2] + scr[3]) * invM;
}

// ---------------- Stage B: lane-group path (M1 in {512,256,128}) ----------
template <int M1, int LANES>
__device__ __forceinline__ void kB_grp(float2* A, const float2* __restrict__ src,
                                       float2* __restrict__ U1h, float* __restrict__ out,
                                       int n, int b, int c, int j1base, int cnt) {
  constexpr int NR = M1 / LANES;
  constexpr int F = 2048 / M1;
  constexpr int GPW = 64 / LANES;
  const int tid = (int)threadIdx.x;
  const int l = tid & 63, wid = tid >> 6;
  const int g = (GPW == 1) ? 0 : (l / LANES);
  const int ll = l & (LANES - 1);
  const int gi = wid * GPW + g;
  const bool valid = gi < cnt;
  const int j1 = j1base + (valid ? gi : 0);
  float2* Aw = A + gi * M1;
  const float xi = 0.4f * exp2f(-0.125f * (float)j1);
  const float sig = 0.1f * xi;
  const float i2s = 1.0f / (2.0f * sig * sig);
#pragma unroll
  for (int i = 0; i < NR; ++i) {
    const int m = ll + LANES * i;
    float2 acc = make_float2(0.0f, 0.0f);
#pragma unroll
    for (int q = 0; q < F; ++q) {
      const int f = m + q * M1;
      const float fr = (float)(f < 1024 ? f : f - 2048) * (1.0f / 2048.0f);
      const float d = fr - xi;
      const float dd = d * d * i2s;
      if (dd < GCUT) {
        const float gg = __expf(-dd);
        const float2 v = src[f];
        acc.x += v.x * gg; acc.y += v.y * gg;
      }
    }
    Aw[swz(m)] = acc;
  }
  dif_w<M1, true, LANES>(Aw, ll);
#pragma unroll
  for (int i = 0; i < NR; ++i) {
    const int m = ll + LANES * i;
    const float2 zv = Aw[swz(m)];
    Aw[swz(m)] = make_float2(sqrtf(zv.x * zv.x + zv.y * zv.y) * (1.0f / 2048.0f), 0.0f);
  }
  dit_w<M1, LANES>(Aw, ll);
  if (valid) {
    float2* dst = U1h + (size_t)n * U1H_STRIDE + u1h_off(j1);
#pragma unroll
    for (int i = 0; i < NR; ++i) {
      const int m = ll + LANES * i;
      dst[m] = Aw[swz(m)];
    }
  }
  const float invM = 1.0f / (float)M1;
  const float c0 = Aw[0].x * invM;
  const float2 U1 = Aw[1], U2 = Aw[2];
  const float k1 = PHI1 * 2.0f * invM, k2 = PHI2 * 2.0f * invM;
  float part = 0.0f;
#pragma unroll
  for (int i = 0; i < NR; ++i) {
    const int t = ll + LANES * i;
    float sv, cv;
    __sincosf((6.283185307179586f / (float)M1) * (float)t, &sv, &cv);
    float acc = c0 + k1 * (U1.x * cv - U1.y * sv);
    const float c2 = cv * cv - sv * sv, s2 = 2.0f * sv * cv;
    acc += k2 * (U2.x * c2 - U2.y * s2);
    part += __logf(acc + 1e-6f);
  }
  part = wsum<LANES>(part);
  if (ll == 0 && valid) out[((size_t)b * 440 + j1) * 6 + c] = part * invM;
}

// kB_all: 15 classes/signal, heavy-first:
// [0,2)=512 (L64, 4/blk); [2,10)=1024blk; [10]=256 (L32, 8/blk);
// [11,15)=128 (L16, 16/blk) j1 24..79 (last class half-padded).
__global__ __launch_bounds__(NTH, 8) void kB_all(const float2* __restrict__ xh,
                                                 float2* __restrict__ U1h,
                                                 float* __restrict__ out) {
  __shared__ float2 A[2048];  // 16384 B
  const int ci = (int)blockIdx.x / 48;
  const int n  = (int)blockIdx.x % 48;
  const int b = n / 6, c = n % 6;
  const float2* src = xh + (size_t)n * 2048;
  if (ci < 2)       kB_grp<512, 64>(A, src, U1h, out, n, b, c, 8 + 4 * ci, 4);
  else if (ci < 10) kB_blk(A, src, U1h, out, n, b, c, ci - 2);
  else if (ci < 11) kB_grp<256, 32>(A, src, U1h, out, n, b, c, 16, 8);
  else {
    const int base = 24 + 16 * (ci - 11);
    kB_grp<128, 16>(A, src, U1h, out, n, b, c, base, min(16, 80 - base));
  }
}

// ---------------- Stage C: block-wide (M2 = 1024, k = 1) ----------------
__device__ __forceinline__ void kC_blk(float2* A, const float2* __restrict__ V,
                                       float* __restrict__ outp, float xi) {
  constexpr int M2 = 1024;
  constexpr int NR2 = M2 / NTH;
  const int tid = (int)threadIdx.x;
  const float sg = 0.8f * xi;
  const float i2s = 1.0f / (2.0f * sg * sg);
#pragma unroll
  for (int ii = 0; ii < NR2; ++ii) {
    const int m = tid + NTH * ii;
    const float fr = (float)(m < 512 ? m : m - 1024) * (1.0f / 2048.0f);
    const float d = fr - xi;
    const float dd = d * d * i2s;
    float2 acc = make_float2(0.0f, 0.0f);
    if (dd < GCUT) {
      const float g = __expf(-dd);
      const float2 vv = V[m];
      acc.x = vv.x * g; acc.y = vv.y * g;
    }
    A[swz(m)] = acc;
  }
  dif_blk<M2, true>(A);  // z2 in P-order
  const float invM1f = 1.0f / 1024.0f;
  float b0 = 0, b1r = 0, b1i = 0, b2r = 0, b2i = 0;
  float cvs[NR2], svs[NR2];
#pragma unroll
  for (int ii = 0; ii < NR2; ++ii) {
    const int idx = tid + NTH * ii;
    const float2 zv = A[swz(idx)];
    const float u = sqrtf(zv.x * zv.x + zv.y * zv.y) * invM1f;
    const int t = prevM<M2>(idx);
    float sv, cv;
    __sincosf((6.283185307179586f / (float)M2) * (float)t, &sv, &cv);
    cvs[ii] = cv; svs[ii] = sv;
    b0 += u;
    b1r += u * cv; b1i -= u * sv;
    const float c2 = cv * cv - sv * sv, s2 = 2.0f * sv * cv;
    b2r += u * c2; b2i -= u * s2;
  }
  b0 = wsum<64>(b0);
  b1r = wsum<64>(b1r); b1i = wsum<64>(b1i);
  b2r = wsum<64>(b2r); b2i = wsum<64>(b2i);
  __syncthreads();
  float* scr = (float*)A;
  const int lane = tid & 63, wid = tid >> 6;
  if (lane == 0) {
    scr[wid * 5 + 0] = b0;
    scr[wid * 5 + 1] = b1r; scr[wid * 5 + 2] = b1i;
    scr[wid * 5 + 3] = b2r; scr[wid * 5 + 4] = b2i;
  }
  __syncthreads();
  float Bv[5];
#pragma unroll
  for (int bi = 0; bi < 5; ++bi)
    Bv[bi] = scr[bi] + scr[5 + bi] + scr[10 + bi] + scr[15 + bi];
  const float k1 = 2.0f * PHI1, k2 = 2.0f * PHI2;
  const float invM2 = 1.0f / (float)M2;
  float part = 0.0f;
#pragma unroll
  for (int ii = 0; ii < NR2; ++ii) {
    const float cv = cvs[ii], sv = svs[ii];
    float acc = Bv[0] + k1 * (Bv[1] * cv - Bv[2] * sv);
    const float c2 = cv * cv - sv * sv, s2 = 2.0f * sv * cv;
    acc += k2 * (Bv[3] * c2 - Bv[4] * s2);
    part += __logf(acc * invM2 + 1e-6f);
  }
  part = wsum<64>(part);
  if (lane == 0) scr[20 + wid] = part;
  __syncthreads();
  if (tid == 0)
    *outp = (scr[20] + scr[21] + scr[22] + scr[23]) * invM2;
}

// ---------------- Stage C: lane-group path ----------------
template <int M2, int LANES>
__device__ __forceinline__ void kC_grp(float2* A, const float2* __restrict__ base,
                                       float* __restrict__ out, int b, int c,
                                       int k, int j1base, int cnt) {
  constexpr int NR2 = M2 / LANES;
  constexpr int GPW = 64 / LANES;
  const int tid = (int)threadIdx.x;
  const int l = tid & 63, wid = tid >> 6;
  const int g = (GPW == 1) ? 0 : (l / LANES);
  const int ll = l & (LANES - 1);
  const int gi = wid * GPW + g;
  const bool valid = gi < cnt;
  const int j1 = j1base + (valid ? gi : 0);
  const int o = j1 >> 3;
  const int M1 = (o == 0) ? 1024 : (o == 1) ? 512 : (o == 2) ? 256 : 128;
  const int F = M1 / M2;
  float2* Aw = A + gi * M2;
  const float2* V = base + u1h_off(j1);
  const float xi = 0.4f * exp2f(-(float)k);
  const float sg = 0.8f * xi;
  const float i2s = 1.0f / (2.0f * sg * sg);
#pragma unroll
  for (int ii = 0; ii < NR2; ++ii) {
    const int m = ll + LANES * ii;
    float2 acc = make_float2(0.0f, 0.0f);
    for (int q = 0; q < F; ++q) {
      const int f = m + q * M2;
      const float fr = (float)(f < (M1 >> 1) ? f : f - M1) * (1.0f / 2048.0f);
      const float d = fr - xi;
      const float dd = d * d * i2s;
      if (dd < GCUT) {
        const float gg = __expf(-dd);
        const float2 vv = V[f];
        acc.x += vv.x * gg; acc.y += vv.y * gg;
      }
    }
    Aw[swz(m)] = acc;
  }
  dif_w<M2, true, LANES>(Aw, ll);
  const float invM1f = 1.0f / (float)M1;
  float cvs[NR2], svs[NR2];
  float b0 = 0, b1r = 0, b1i = 0, b2r = 0, b2i = 0;
#pragma unroll
  for (int ii = 0; ii < NR2; ++ii) {
    const int idx = ll + LANES * ii;
    const float2 zv = Aw[swz(idx)];
    const float u = sqrtf(zv.x * zv.x + zv.y * zv.y) * invM1f;
    const int t = prevM<M2>(idx);
    float sv, cv;
    __sincosf((6.283185307179586f / (float)M2) * (float)t, &sv, &cv);
    cvs[ii] = cv; svs[ii] = sv;
    b0 += u;
    b1r += u * cv; b1i -= u * sv;
    const float c2 = cv * cv - sv * sv, s2 = 2.0f * sv * cv;
    b2r += u * c2; b2i -= u * s2;
  }
  b0 = wsum<LANES>(b0);
  b1r = wsum<LANES>(b1r); b1i = wsum<LANES>(b1i);
  b2r = wsum<LANES>(b2r); b2i = wsum<LANES>(b2i);
  const float k1 = 2.0f * PHI1, k2 = 2.0f * PHI2;
  const float invM2 = 1.0f / (float)M2;
  float part = 0.0f;
#pragma unroll
  for (int ii = 0; ii < NR2; ++ii) {
    const float cv = cvs[ii], sv = svs[ii];
    float acc = b0 + k1 * (b1r * cv - b1i * sv);
    const float c2 = cv * cv - sv * sv, s2 = 2.0f * sv * cv;
    acc += k2 * (b2r * c2 - b2i * s2);
    part += __logf(acc * invM2 + 1e-6f);
  }
  part = wsum<LANES>(part);
  if (ll == 0 && valid) {
    const int p = 4 * k * (k - 1) + j1;
    out[((size_t)b * 440 + 80 + p) * 6 + c] = part * invM2;
  }
}

// kC_all: 38 classes/signal, heavy-first. Schedule (per r12): k1:1024,
// k2:512, k3:512(o0)/256, k4:256(o0)/128, k>=5:128.
// [0,4)=k2 512 j1 0-15; [4,6)=k3 512 j1 0-7; [6,14)=k1 1024blk;
// [14,16)=k3 256 j1 8-23; [16]=k4 256 j1 0-7; [17,19)=k4 128 j1 8-31;
// [19,38)=k5..9 128 quads (3,3,4,4,5 classes).
__global__ __launch_bounds__(NTH, 8) void kC_all(const float2* __restrict__ U1h,
                                                 float* __restrict__ out) {
  __shared__ float2 A[2048];  // 16384 B
  const int ci = (int)blockIdx.x / 48;
  const int n  = (int)blockIdx.x % 48;
  const int b = n / 6, c = n % 6;
  const float2* base = U1h + (size_t)n * U1H_STRIDE;
  if (ci < 4) {
    kC_grp<512, 64>(A, base, out, b, c, 2, 4 * ci, 4);
  } else if (ci < 6) {
    kC_grp<512, 64>(A, base, out, b, c, 3, 4 * (ci - 4), 4);
  } else if (ci < 14) {
    const int j1 = ci - 6;
    const float xi = 0.4f * exp2f(-1.0f);
    const int p = j1;  // 4*1*0 + j1
    kC_blk(A, base + u1h_off(j1), out + ((size_t)b * 440 + 80 + p) * 6 + c, xi);
  } else if (ci < 16) {
    kC_grp<256, 32>(A, base, out, b, c, 3, 8 + 8 * (ci - 14), 8);
  } else if (ci < 17) {
    kC_grp<256, 32>(A, base, out, b, c, 4, 0, 8);
  } else if (ci < 19) {
    const int jb = 8 + 16 * (ci - 17);
    kC_grp<128, 16>(A, base, out, b, c, 4, jb, min(16, 32 - jb));
  } else {
    int g = ci - 19;  // per k=5..9: ceil(8k/16) classes = 3,3,4,4,5
    int k = 5, nb = 3;
    while (g >= nb) { g -= nb; ++k; nb = (8 * k + 15) / 16; }
    const int jb = 16 * g;
    kC_grp<128, 16>(A, base, out, b, c, k, jb, min(16, 8 * k - jb));
  }
}

extern "C" void kernel_launch(void* const* d_in, const int* in_sizes, int n_in,
                              void* d_out, int out_size, void* d_ws, size_t ws_size,
                              hipStream_t stream) {
  (void)in_sizes; (void)n_in; (void)out_size; (void)ws_size;
  const float* x = (const float*)d_in[0];  // [8, 2048, 6] fp32
  float* out = (float*)d_out;              // [8, 440, 6] fp32
  float2* U1h = (float2*)d_ws;                                       // 8.1 MB
  float2* xh = (float2*)((char*)d_ws + (size_t)48 * U1H_STRIDE * sizeof(float2));
  kA<<<dim3(48), dim3(NTH), 0, stream>>>(x, xh);
  kB_all<<<dim3(15 * 48), dim3(NTH), 0, stream>>>(xh, U1h, out);
  kC_all<<<dim3(38 * 48), dim3(NTH), 0, stream>>>(U1h, out);
}

// Round 15
// 93.959 us; speedup vs baseline: 1.0228x; 1.0228x over previous
//
#include <hip/hip_runtime.h>

#define NTH 256
#define U1H_STRIDE 21504  // 8*1024 + 8*512 + 8*256 + 8*128 + 48*128

#define PHI1 0.29504296f    // e^{-1.220703125}
#define PHI2 0.0075683594f  // e^{-4.8828125}
#define GCUT 18.0f          // Gaussian support cutoff: e^-18 = 1.5e-8

// Bank swizzle — conflict-free for all in-place strides; swz(i+128)=swz(i)+128
// so 128-aligned group regions preserve the pattern (verified r5-r12).
__device__ __forceinline__ int swz(int i) { return i ^ (((i >> 4) & 3) * 5); }

__device__ __forceinline__ float2 cmul(float2 a, float2 b) {
  return make_float2(a.x * b.x - a.y * b.y, a.x * b.y + a.y * b.x);
}

template <int W>
__device__ __forceinline__ float wsum(float v) {
#pragma unroll
  for (int off = 1; off < W; off <<= 1) v += __shfl_xor(v, off, 64);
  return v;
}

// P(idx): output frequency of storage slot idx after the DIF stage sequence.
template <int M>
__device__ __forceinline__ int prevM(int i) {
  if (M == 128)
    return ((i >> 5) & 3) | (((i >> 3) & 3) << 2) | (((i >> 1) & 3) << 4) | ((i & 1) << 6);
  else if (M == 256)
    return ((i & 3) << 6) | (((i >> 2) & 3) << 4) | (((i >> 4) & 3) << 2) | ((i >> 6) & 3);
  else if (M == 512)
    return ((i >> 7) & 3) | (((i >> 5) & 3) << 2) | (((i >> 3) & 3) << 4) |
           (((i >> 1) & 3) << 6) | ((i & 1) << 8);
  else if (M == 1024)
    return ((i >> 8) & 3) | (((i >> 6) & 3) << 2) | (((i >> 4) & 3) << 4) |
           (((i >> 2) & 3) << 6) | ((i & 3) << 8);
  else
    return ((i >> 9) & 3) | (((i >> 7) & 3) << 2) | (((i >> 5) & 3) << 4) |
           (((i >> 3) & 3) << 6) | (((i >> 1) & 3) << 8) | ((i & 1) << 10);
}

// In-place radix-4 DIF stage; twiddles in registers.
template <bool INV>
__device__ __forceinline__ void dif4(float2* A, int j, int ls, float astep) {
  const int s = 1 << ls;
  const int e = j & (s - 1);
  const int base = ((j >> ls) << (ls + 2)) | e;
  float2 w1;
  __sincosf(astep * (float)e, &w1.y, &w1.x);
  if (INV) w1.y = -w1.y;
  const float2 w2 = cmul(w1, w1);
  const float2 w3 = cmul(w2, w1);
  const float2 a0 = A[swz(base)];
  const float2 a1 = A[swz(base + s)];
  const float2 a2 = A[swz(base + 2 * s)];
  const float2 a3 = A[swz(base + 3 * s)];
  const float t0x = a0.x + a2.x, t0y = a0.y + a2.y;
  const float t1x = a0.x - a2.x, t1y = a0.y - a2.y;
  const float t2x = a1.x + a3.x, t2y = a1.y + a3.y;
  const float bdx = a1.x - a3.x, bdy = a1.y - a3.y;
  const float sgn = INV ? -1.0f : 1.0f;
  const float t3x = sgn * bdy, t3y = -sgn * bdx;
  A[swz(base)]         = make_float2(t0x + t2x, t0y + t2y);
  A[swz(base + s)]     = cmul(make_float2(t1x + t3x, t1y + t3y), w1);
  A[swz(base + 2 * s)] = cmul(make_float2(t0x - t2x, t0y - t2y), w2);
  A[swz(base + 3 * s)] = cmul(make_float2(t1x - t3x, t1y - t3y), w3);
}

// In-place radix-4 DIT stage (transpose network; forward only).
__device__ __forceinline__ void dit4(float2* A, int j, int ls, float astep) {
  const int s = 1 << ls;
  const int e = j & (s - 1);
  const int base = ((j >> ls) << (ls + 2)) | e;
  float2 w1;
  __sincosf(astep * (float)e, &w1.y, &w1.x);
  const float2 w2 = cmul(w1, w1);
  const float2 w3 = cmul(w2, w1);
  const float2 c0 = A[swz(base)];
  const float2 c1 = cmul(A[swz(base + s)], w1);
  const float2 c2 = cmul(A[swz(base + 2 * s)], w2);
  const float2 c3 = cmul(A[swz(base + 3 * s)], w3);
  const float t0x = c0.x + c2.x, t0y = c0.y + c2.y;
  const float t1x = c0.x - c2.x, t1y = c0.y - c2.y;
  const float t2x = c1.x + c3.x, t2y = c1.y + c3.y;
  const float bdx = c1.x - c3.x, bdy = c1.y - c3.y;
  const float t3x = bdy, t3y = -bdx;
  A[swz(base)]         = make_float2(t0x + t2x, t0y + t2y);
  A[swz(base + s)]     = make_float2(t1x + t3x, t1y + t3y);
  A[swz(base + 2 * s)] = make_float2(t0x - t2x, t0y - t2y);
  A[swz(base + 3 * s)] = make_float2(t1x - t3x, t1y - t3y);
}

__device__ __forceinline__ void r2pair(float2* A, int g) {
  const float2 a = A[swz(2 * g)];
  const float2 b = A[swz(2 * g + 1)];
  A[swz(2 * g)]     = make_float2(a.x + b.x, a.y + b.y);
  A[swz(2 * g + 1)] = make_float2(a.x - b.x, a.y - b.y);
}

template <int M> struct LMof { static constexpr int v =
  (M == 2048) ? 11 : (M == 1024) ? 10 : (M == 512) ? 9 : (M == 256) ? 8 : 7; };

// Block-wide in-place DIF: natural -> P-order. M in {1024, 2048}.
template <int M, bool INV>
__device__ __forceinline__ void dif_blk(float2* A) {
  constexpr int LM = LMof<M>::v;
  constexpr int NB = M / 4;
  const int tid = (int)threadIdx.x;
#pragma unroll
  for (int ls = LM - 2; ls >= (LM & 1); ls -= 2) {
    const float astep = -1.5707963267948966f / (float)(1 << ls);
    __syncthreads();
#pragma unroll
    for (int i = 0; i < NB / NTH; ++i) dif4<INV>(A, tid + NTH * i, ls, astep);
  }
  if (LM & 1) {
    __syncthreads();
#pragma unroll
    for (int i = 0; i < (M / 2) / NTH; ++i) r2pair(A, tid + NTH * i);
  }
  __syncthreads();
}

// Block-wide in-place DIT (forward): P-order -> natural.
template <int M>
__device__ __forceinline__ void dit_blk(float2* A) {
  constexpr int LM = LMof<M>::v;
  constexpr int NB = M / 4;
  const int tid = (int)threadIdx.x;
  if (LM & 1) {
    __syncthreads();
#pragma unroll
    for (int i = 0; i < (M / 2) / NTH; ++i) r2pair(A, tid + NTH * i);
  }
#pragma unroll
  for (int ls = (LM & 1); ls <= LM - 2; ls += 2) {
    const float astep = -1.5707963267948966f / (float)(1 << ls);
    __syncthreads();
#pragma unroll
    for (int i = 0; i < NB / NTH; ++i) dit4(A, tid + NTH * i, ls, astep);
  }
  __syncthreads();
}

// Lane-group FFTs, barrier-free (group-private slice, in-order LDS pipe).
template <int M, bool INV, int LANES>
__device__ __forceinline__ void dif_w(float2* Aw, int l) {
  constexpr int LM = LMof<M>::v;
  constexpr int NB = M / 4;
#pragma unroll
  for (int ls = LM - 2; ls >= (LM & 1); ls -= 2) {
    const float astep = -1.5707963267948966f / (float)(1 << ls);
#pragma unroll
    for (int i = 0; i < NB / LANES; ++i) dif4<INV>(Aw, l + LANES * i, ls, astep);
  }
  if (LM & 1) {
#pragma unroll
    for (int i = 0; i < (M / 2) / LANES; ++i) r2pair(Aw, l + LANES * i);
  }
}

template <int M, int LANES>
__device__ __forceinline__ void dit_w(float2* Aw, int l) {
  constexpr int LM = LMof<M>::v;
  constexpr int NB = M / 4;
  if (LM & 1) {
#pragma unroll
    for (int i = 0; i < (M / 2) / LANES; ++i) r2pair(Aw, l + LANES * i);
  }
#pragma unroll
  for (int ls = (LM & 1); ls <= LM - 2; ls += 2) {
    const float astep = -1.5707963267948966f / (float)(1 << ls);
#pragma unroll
    for (int i = 0; i < NB / LANES; ++i) dit4(Aw, l + LANES * i, ls, astep);
  }
}

// U1h layout: o=0:1024/path; o=1:512; o=2:256; o>=3:128.
__device__ __forceinline__ int u1h_off(int j1) {
  const int o = j1 >> 3;
  if (o == 0) return j1 * 1024;
  if (o == 1) return 8192 + (j1 - 8) * 512;
  if (o == 2) return 12288 + (j1 - 16) * 256;
  return 14336 + (j1 - 24) * 128;
}

// ---------------- Stage A ----------------
__global__ __launch_bounds__(NTH) void kA(const float* __restrict__ x,
                                          float2* __restrict__ xh) {
  __shared__ float2 A[2048];
  const int n = blockIdx.x, b = n / 6, c = n % 6;
  const float* xp = x + (size_t)b * (2048 * 6) + c;
#pragma unroll
  for (int i = 0; i < 8; ++i) {
    const int t = (int)threadIdx.x + NTH * i;
    A[swz(t)] = make_float2(xp[t * 6], 0.0f);
  }
  dif_blk<2048, false>(A);
#pragma unroll
  for (int i = 0; i < 8; ++i) {
    const int t = (int)threadIdx.x + NTH * i;
    xh[(size_t)n * 2048 + prevM<2048>(t)] = A[swz(t)];
  }
}

// ---------------- Stage B bodies ----------------
template <int M1>
__device__ __forceinline__ void kB_blk(float2* A, const float2* __restrict__ src,
                                       float2* __restrict__ U1h, float* __restrict__ out,
                                       int n, int b, int c, int j1) {
  constexpr int F = 2048 / M1;
  constexpr int NR = M1 / NTH;
  const int tid = (int)threadIdx.x;
  const float xi = 0.4f * exp2f(-0.125f * (float)j1);
  const float sig = 0.1f * xi;
  const float i2s = 1.0f / (2.0f * sig * sig);
#pragma unroll
  for (int i = 0; i < NR; ++i) {
    const int m = tid + NTH * i;
    float2 acc = make_float2(0.0f, 0.0f);
#pragma unroll
    for (int q = 0; q < F; ++q) {
      const int f = m + q * M1;
      const float fr = (float)(f < 1024 ? f : f - 2048) * (1.0f / 2048.0f);
      const float d = fr - xi;
      const float dd = d * d * i2s;
      if (dd < GCUT) {
        const float g = __expf(-dd);
        const float2 v = src[f];
        acc.x += v.x * g; acc.y += v.y * g;
      }
    }
    A[swz(m)] = acc;
  }
  dif_blk<M1, true>(A);
#pragma unroll
  for (int i = 0; i < NR; ++i) {
    const int m = tid + NTH * i;
    const float2 zv = A[swz(m)];
    A[swz(m)] = make_float2(sqrtf(zv.x * zv.x + zv.y * zv.y) * (1.0f / 2048.0f), 0.0f);
  }
  dit_blk<M1>(A);  // V natural (digit reversal cancels)
  float2* dst = U1h + (size_t)n * U1H_STRIDE + u1h_off(j1);
#pragma unroll
  for (int i = 0; i < NR; ++i) {
    const int m = tid + NTH * i;
    dst[m] = A[swz(m)];
  }
  const float invM = 1.0f / (float)M1;
  const float c0 = A[0].x * invM;  // swz identity for idx<16
  const float2 U1 = A[1], U2 = A[2];
  __syncthreads();  // all A[0..2] reads done before scr overlay
  const float k1 = PHI1 * 2.0f * invM, k2 = PHI2 * 2.0f * invM;
  float part = 0.0f;
#pragma unroll
  for (int i = 0; i < NR; ++i) {
    const int t = tid + NTH * i;
    float sv, cv;
    __sincosf((6.283185307179586f / (float)M1) * (float)t, &sv, &cv);
    float acc = c0 + k1 * (U1.x * cv - U1.y * sv);
    const float c2 = cv * cv - sv * sv, s2 = 2.0f * sv * cv;
    acc += k2 * (U2.x * c2 - U2.y * s2);
    part += __logf(acc + 1e-6f);
  }
  part = wsum<64>(part);
  float* scr = (float*)A;
  const int lane = tid & 63, wid = tid >> 6;
  if (lane == 0) scr[wid] = part;
  __syncthreads();
  if (tid == 0)
    out[((size_t)b * 440 + j1) * 6 + c] = (scr[0] + scr[1] + scr[2] + scr[3]) * invM;
}

template <int M1>
__device__ __forceinline__ void kB_wav(float2* A, const float2* __restrict__ src,
                                       float2* __restrict__ U1h, float* __restrict__ out,
                                       int n, int b, int c, int j1base) {
  constexpr int NRW = M1 / 64;
  constexpr int F = 2048 / M1;
  const int tid = (int)threadIdx.x;
  const int l = tid & 63, wid = tid >> 6;
  const int j1 = j1base + wid;
  float2* Aw = A + wid * M1;
  const float xi = 0.4f * exp2f(-0.125f * (float)j1);
  const float sig = 0.1f * xi;
  const float i2s = 1.0f / (2.0f * sig * sig);
#pragma unroll
  for (int i = 0; i < NRW; ++i) {
    const int m = l + 64 * i;
    float2 acc = make_float2(0.0f, 0.0f);
#pragma unroll
    for (int q = 0; q < F; ++q) {
      const int f = m + q * M1;
      const float fr = (float)(f < 1024 ? f : f - 2048) * (1.0f / 2048.0f);
      const float d = fr - xi;
      const float dd = d * d * i2s;
      if (dd < GCUT) {
        const float g = __expf(-dd);
        const float2 v = src[f];
        acc.x += v.x * g; acc.y += v.y * g;
      }
    }
    Aw[swz(m)] = acc;
  }
  dif_w<M1, true, 64>(Aw, l);
#pragma unroll
  for (int i = 0; i < NRW; ++i) {
    const int m = l + 64 * i;
    const float2 zv = Aw[swz(m)];
    Aw[swz(m)] = make_float2(sqrtf(zv.x * zv.x + zv.y * zv.y) * (1.0f / 2048.0f), 0.0f);
  }
  dit_w<M1, 64>(Aw, l);
  float2* dst = U1h + (size_t)n * U1H_STRIDE + u1h_off(j1);
#pragma unroll
  for (int i = 0; i < NRW; ++i) {
    const int m = l + 64 * i;
    dst[m] = Aw[swz(m)];
  }
  const float invM = 1.0f / (float)M1;
  const float c0 = Aw[0].x * invM;
  const float2 U1 = Aw[1], U2 = Aw[2];
  const float k1 = PHI1 * 2.0f * invM, k2 = PHI2 * 2.0f * invM;
  float part = 0.0f;
#pragma unroll
  for (int i = 0; i < NRW; ++i) {
    const int t = l + 64 * i;
    float sv, cv;
    __sincosf((6.283185307179586f / (float)M1) * (float)t, &sv, &cv);
    float acc = c0 + k1 * (U1.x * cv - U1.y * sv);
    const float c2 = cv * cv - sv * sv, s2 = 2.0f * sv * cv;
    acc += k2 * (U2.x * c2 - U2.y * s2);
    part += __logf(acc + 1e-6f);
  }
  part = wsum<64>(part);
  if (l == 0) out[((size_t)b * 440 + j1) * 6 + c] = part * invM;
}

// Dual per-wave B path: two 128-pt paths per wave (half-wave each).
__device__ __forceinline__ void kB_dual(float2* A, const float2* __restrict__ src,
                                        float2* __restrict__ U1h, float* __restrict__ out,
                                        int n, int b, int c, int j1base) {
  const int tid = (int)threadIdx.x;
  const int l = tid & 63, wid = tid >> 6;
  const int h = l >> 5, ll = l & 31;
  const int j1 = j1base + 2 * wid + h;
  float2* Ah = A + wid * 256 + h * 128;
  const float xi = 0.4f * exp2f(-0.125f * (float)j1);
  const float sig = 0.1f * xi;
  const float i2s = 1.0f / (2.0f * sig * sig);
#pragma unroll
  for (int i = 0; i < 4; ++i) {
    const int m = ll + 32 * i;
    float2 acc = make_float2(0.0f, 0.0f);
#pragma unroll
    for (int q = 0; q < 16; ++q) {
      const int f = m + q * 128;
      const float fr = (float)(f < 1024 ? f : f - 2048) * (1.0f / 2048.0f);
      const float d = fr - xi;
      const float dd = d * d * i2s;
      if (dd < GCUT) {
        const float g = __expf(-dd);
        const float2 v = src[f];
        acc.x += v.x * g; acc.y += v.y * g;
      }
    }
    Ah[swz(m)] = acc;
  }
  dif_w<128, true, 32>(Ah, ll);
#pragma unroll
  for (int i = 0; i < 4; ++i) {
    const int m = ll + 32 * i;
    const float2 zv = Ah[swz(m)];
    Ah[swz(m)] = make_float2(sqrtf(zv.x * zv.x + zv.y * zv.y) * (1.0f / 2048.0f), 0.0f);
  }
  dit_w<128, 32>(Ah, ll);
  float2* dst = U1h + (size_t)n * U1H_STRIDE + u1h_off(j1);
#pragma unroll
  for (int i = 0; i < 4; ++i) {
    const int m = ll + 32 * i;
    dst[m] = Ah[swz(m)];
  }
  const float invM = 1.0f / 128.0f;
  const float c0 = Ah[0].x * invM;
  const float2 U1 = Ah[1], U2 = Ah[2];
  const float k1 = PHI1 * 2.0f * invM, k2 = PHI2 * 2.0f * invM;
  float part = 0.0f;
#pragma unroll
  for (int i = 0; i < 4; ++i) {
    const int t = ll + 32 * i;
    float sv, cv;
    __sincosf((6.283185307179586f / 128.0f) * (float)t, &sv, &cv);
    float acc = c0 + k1 * (U1.x * cv - U1.y * sv);
    const float c2 = cv * cv - sv * sv, s2 = 2.0f * sv * cv;
    acc += k2 * (U2.x * c2 - U2.y * s2);
    part += __logf(acc + 1e-6f);
  }
  part = wsum<32>(part);
  if (ll == 0) out[((size_t)b * 440 + j1) * 6 + c] = part * invM;
}

// kB_all: 19 classes/signal, heavy-first:
// [0,2)=512wav j1 8-15; [2,10)=1024blk j1 0-7; [10,12)=256wav j1 16-23;
// [12,19)=128dual j1 24-79.
__global__ __launch_bounds__(NTH, 8) void kB_all(const float2* __restrict__ xh,
                                                 float2* __restrict__ U1h,
                                                 float* __restrict__ out) {
  __shared__ float2 A[2048];  // 16384 B
  const int ci = (int)blockIdx.x / 48;
  const int n  = (int)blockIdx.x % 48;
  const int b = n / 6, c = n % 6;
  const float2* src = xh + (size_t)n * 2048;
  if (ci < 2)       kB_wav<512>(A, src, U1h, out, n, b, c, 8 + 4 * ci);
  else if (ci < 10) kB_blk<1024>(A, src, U1h, out, n, b, c, ci - 2);
  else if (ci < 12) kB_wav<256>(A, src, U1h, out, n, b, c, 16 + 4 * (ci - 10));
  else              kB_dual(A, src, U1h, out, n, b, c, 24 + 8 * (ci - 12));
}

// ---------------- Stage C bodies (3-bin direct DFT; fold from global V) -----
template <int M2>
__device__ __forceinline__ void kC_blk(float2* A, const float2* __restrict__ V,
                                       float* __restrict__ outp, int M1, int F, float xi) {
  constexpr int NR2 = M2 / NTH;
  const int tid = (int)threadIdx.x;
  const float sg = 0.8f * xi;
  const float i2s = 1.0f / (2.0f * sg * sg);
#pragma unroll
  for (int ii = 0; ii < NR2; ++ii) {
    const int m = tid + NTH * ii;
    float2 acc = make_float2(0.0f, 0.0f);
    for (int q = 0; q < F; ++q) {
      const int f = m + q * M2;
      const float fr = (float)(f < (M1 >> 1) ? f : f - M1) * (1.0f / 2048.0f);
      const float d = fr - xi;
      const float dd = d * d * i2s;
      if (dd < GCUT) {
        const float g = __expf(-dd);
        const float2 vv = V[f];
        acc.x += vv.x * g; acc.y += vv.y * g;
      }
    }
    A[swz(m)] = acc;
  }
  dif_blk<M2, true>(A);  // z2 in P-order
  const float invM1f = 1.0f / (float)M1;
  float b0 = 0, b1r = 0, b1i = 0, b2r = 0, b2i = 0;
#pragma unroll
  for (int ii = 0; ii < NR2; ++ii) {
    const int idx = tid + NTH * ii;
    const float2 zv = A[swz(idx)];
    const float u = sqrtf(zv.x * zv.x + zv.y * zv.y) * invM1f;
    const int t = prevM<M2>(idx);
    float sv, cv;
    __sincosf((6.283185307179586f / (float)M2) * (float)t, &sv, &cv);
    b0 += u;
    b1r += u * cv; b1i -= u * sv;
    const float c2 = cv * cv - sv * sv, s2 = 2.0f * sv * cv;
    b2r += u * c2; b2i -= u * s2;
  }
  b0 = wsum<64>(b0);
  b1r = wsum<64>(b1r); b1i = wsum<64>(b1i);
  b2r = wsum<64>(b2r); b2i = wsum<64>(b2i);
  __syncthreads();  // all phase-1 A reads done
  float* scr = (float*)A;
  const int lane = tid & 63, wid = tid >> 6;
  if (lane == 0) {
    scr[wid * 5 + 0] = b0;
    scr[wid * 5 + 1] = b1r; scr[wid * 5 + 2] = b1i;
    scr[wid * 5 + 3] = b2r; scr[wid * 5 + 4] = b2i;
  }
  __syncthreads();
  float Bv[5];
#pragma unroll
  for (int bi = 0; bi < 5; ++bi)
    Bv[bi] = scr[bi] + scr[5 + bi] + scr[10 + bi] + scr[15 + bi];
  const float k1 = 2.0f * PHI1, k2 = 2.0f * PHI2;
  const float invM2 = 1.0f / (float)M2;
  float part = 0.0f;
#pragma unroll
  for (int ii = 0; ii < NR2; ++ii) {
    const int idx = tid + NTH * ii;
    const int t = prevM<M2>(idx);
    float sv, cv;
    __sincosf((6.283185307179586f / (float)M2) * (float)t, &sv, &cv);
    float acc = Bv[0] + k1 * (Bv[1] * cv - Bv[2] * sv);
    const float c2 = cv * cv - sv * sv, s2 = 2.0f * sv * cv;
    acc += k2 * (Bv[3] * c2 - Bv[4] * s2);
    part += __logf(acc * invM2 + 1e-6f);
  }
  part = wsum<64>(part);
  if (lane == 0) scr[20 + wid] = part;
  __syncthreads();
  if (tid == 0)
    *outp = (scr[20] + scr[21] + scr[22] + scr[23]) * invM2;
}

template <int M2>
__device__ __forceinline__ void kC_wav(float2* Aw, const float2* __restrict__ V,
                                       float* __restrict__ outp, int M1, int F,
                                       float xi, int l) {
  constexpr int NR2 = M2 / 64;
  const float sg = 0.8f * xi;
  const float i2s = 1.0f / (2.0f * sg * sg);
#pragma unroll
  for (int ii = 0; ii < NR2; ++ii) {
    const int m = l + 64 * ii;
    float2 acc = make_float2(0.0f, 0.0f);
    for (int q = 0; q < F; ++q) {
      const int f = m + q * M2;
      const float fr = (float)(f < (M1 >> 1) ? f : f - M1) * (1.0f / 2048.0f);
      const float d = fr - xi;
      const float dd = d * d * i2s;
      if (dd < GCUT) {
        const float g = __expf(-dd);
        const float2 vv = V[f];
        acc.x += vv.x * g; acc.y += vv.y * g;
      }
    }
    Aw[swz(m)] = acc;
  }
  dif_w<M2, true, 64>(Aw, l);
  const float invM1f = 1.0f / (float)M1;
  float cvs[NR2], svs[NR2];
  float b0 = 0, b1r = 0, b1i = 0, b2r = 0, b2i = 0;
#pragma unroll
  for (int ii = 0; ii < NR2; ++ii) {
    const int idx = l + 64 * ii;
    const float2 zv = Aw[swz(idx)];
    const float u = sqrtf(zv.x * zv.x + zv.y * zv.y) * invM1f;
    const int t = prevM<M2>(idx);
    float sv, cv;
    __sincosf((6.283185307179586f / (float)M2) * (float)t, &sv, &cv);
    cvs[ii] = cv; svs[ii] = sv;
    b0 += u;
    b1r += u * cv; b1i -= u * sv;
    const float c2 = cv * cv - sv * sv, s2 = 2.0f * sv * cv;
    b2r += u * c2; b2i -= u * s2;
  }
  b0 = wsum<64>(b0);
  b1r = wsum<64>(b1r); b1i = wsum<64>(b1i);
  b2r = wsum<64>(b2r); b2i = wsum<64>(b2i);
  const float k1 = 2.0f * PHI1, k2 = 2.0f * PHI2;
  const float invM2 = 1.0f / (float)M2;
  float part = 0.0f;
#pragma unroll
  for (int ii = 0; ii < NR2; ++ii) {
    const float cv = cvs[ii], sv = svs[ii];
    float acc = b0 + k1 * (b1r * cv - b1i * sv);
    const float c2 = cv * cv - sv * sv, s2 = 2.0f * sv * cv;
    acc += k2 * (b2r * c2 - b2i * s2);
    part += __logf(acc * invM2 + 1e-6f);
  }
  part = wsum<64>(part);
  if (l == 0) *outp = part * invM2;
}

// Dual per-wave C step (M2=128, two paths per wave).
__device__ __forceinline__ void kC_dual(float2* Ah, const float2* __restrict__ V,
                                        float* __restrict__ outp, int M1, int F,
                                        float xi, int ll) {
  const float sg = 0.8f * xi;
  const float i2s = 1.0f / (2.0f * sg * sg);
#pragma unroll
  for (int ii = 0; ii < 4; ++ii) {
    const int m = ll + 32 * ii;
    float2 acc = make_float2(0.0f, 0.0f);
    for (int q = 0; q < F; ++q) {
      const int f = m + q * 128;
      const float fr = (float)(f < (M1 >> 1) ? f : f - M1) * (1.0f / 2048.0f);
      const float d = fr - xi;
      const float dd = d * d * i2s;
      if (dd < GCUT) {
        const float g = __expf(-dd);
        const float2 vv = V[f];
        acc.x += vv.x * g; acc.y += vv.y * g;
      }
    }
    Ah[swz(m)] = acc;
  }
  dif_w<128, true, 32>(Ah, ll);
  const float invM1f = 1.0f / (float)M1;
  float cvs[4], svs[4];
  float b0 = 0, b1r = 0, b1i = 0, b2r = 0, b2i = 0;
#pragma unroll
  for (int ii = 0; ii < 4; ++ii) {
    const int idx = ll + 32 * ii;
    const float2 zv = Ah[swz(idx)];
    const float u = sqrtf(zv.x * zv.x + zv.y * zv.y) * invM1f;
    const int t = prevM<128>(idx);
    float sv, cv;
    __sincosf((6.283185307179586f / 128.0f) * (float)t, &sv, &cv);
    cvs[ii] = cv; svs[ii] = sv;
    b0 += u;
    b1r += u * cv; b1i -= u * sv;
    const float c2 = cv * cv - sv * sv, s2 = 2.0f * sv * cv;
    b2r += u * c2; b2i -= u * s2;
  }
  b0 = wsum<32>(b0);
  b1r = wsum<32>(b1r); b1i = wsum<32>(b1i);
  b2r = wsum<32>(b2r); b2i = wsum<32>(b2i);
  const float k1 = 2.0f * PHI1, k2 = 2.0f * PHI2;
  const float invM2 = 1.0f / 128.0f;
  float part = 0.0f;
#pragma unroll
  for (int ii = 0; ii < 4; ++ii) {
    const float cv = cvs[ii], sv = svs[ii];
    float acc = b0 + k1 * (b1r * cv - b1i * sv);
    const float c2 = cv * cv - sv * sv, s2 = 2.0f * sv * cv;
    acc += k2 * (b2r * c2 - b2i * s2);
    part += __logf(acc * invM2 + 1e-6f);
  }
  part = wsum<32>(part);
  if (ll == 0) *outp = part * invM2;
}

// kC_all: 58 classes/signal, heavy-first (schedule: k1:1024, k2:512,
// k3:512(o0)/256, k4:256(o0)/128, k>=5:128):
// [0,4)=k2 512wav j1 0-15; [4,6)=k3 512wav j1 0-7; [6,14)=k1 1024blk;
// [14,18)=k3 256wav j1 8-23; [18,20)=k4 256wav j1 0-7;
// [20,23)=k4 128dual j1 8-31; [23,58)=k5..9 128dual.
__global__ __launch_bounds__(NTH, 8) void kC_all(const float2* __restrict__ U1h,
                                                 float* __restrict__ out) {
  __shared__ float2 A[2048];  // 16384 B
  const int ci = (int)blockIdx.x / 48;
  const int n  = (int)blockIdx.x % 48;
  const int b = n / 6, c = n % 6;
  const float2* base = U1h + (size_t)n * U1H_STRIDE;
  const int wid = (int)threadIdx.x >> 6;
  const int l = (int)threadIdx.x & 63;
  if (ci < 4) {
    const int k = 2;
    const int j1 = 4 * ci + wid;  // 0..15
    const int M1 = (j1 < 8) ? 1024 : 512;
    const float xi = 0.4f * exp2f(-(float)k);
    const int p = 4 * k * (k - 1) + j1;
    kC_wav<512>(A + wid * 512, base + u1h_off(j1),
                out + ((size_t)b * 440 + 80 + p) * 6 + c, M1, M1 / 512, xi, l);
  } else if (ci < 6) {
    const int k = 3;
    const int j1 = 4 * (ci - 4) + wid;  // 0..7
    const float xi = 0.4f * exp2f(-(float)k);
    const int p = 4 * k * (k - 1) + j1;
    kC_wav<512>(A + wid * 512, base + u1h_off(j1),
                out + ((size_t)b * 440 + 80 + p) * 6 + c, 1024, 2, xi, l);
  } else if (ci < 14) {
    const int k = 1;
    const int j1 = ci - 6;  // 0..7
    const float xi = 0.4f * exp2f(-(float)k);
    const int p = 4 * k * (k - 1) + j1;
    kC_blk<1024>(A, base + u1h_off(j1), out + ((size_t)b * 440 + 80 + p) * 6 + c,
                 1024, 1, xi);
  } else if (ci < 18) {
    const int k = 3;
    const int j1 = 8 + 4 * (ci - 14) + wid;  // 8..23
    const int M1 = (j1 < 16) ? 512 : 256;
    const float xi = 0.4f * exp2f(-(float)k);
    const int p = 4 * k * (k - 1) + j1;
    kC_wav<256>(A + wid * 256, base + u1h_off(j1),
                out + ((size_t)b * 440 + 80 + p) * 6 + c, M1, M1 / 256, xi, l);
  } else if (ci < 20) {
    const int k = 4;
    const int j1 = 4 * (ci - 18) + wid;  // 0..7
    const float xi = 0.4f * exp2f(-(float)k);
    const int p = 4 * k * (k - 1) + j1;
    kC_wav<256>(A + wid * 256, base + u1h_off(j1),
                out + ((size_t)b * 440 + 80 + p) * 6 + c, 1024, 4, xi, l);
  } else if (ci < 23) {
    const int k = 4;
    const int h = l >> 5, ll = l & 31;
    const int j1 = 8 + 8 * (ci - 20) + 2 * wid + h;  // 8..31
    const int o = j1 >> 3;                           // 1..3
    const int M1 = (o < 3) ? (1024 >> o) : 128;
    const float xi = 0.4f * exp2f(-(float)k);
    const int p = 4 * k * (k - 1) + j1;
    kC_dual(A + wid * 256 + h * 128, base + u1h_off(j1),
            out + ((size_t)b * 440 + 80 + p) * 6 + c, M1, M1 / 128, xi, ll);
  } else {
    int g = ci - 23;  // k classes for each k=5..9 (8k paths / 8 per block)
    int k = 5;
    while (g >= k) { g -= k; ++k; }
    const int h = l >> 5, ll = l & 31;
    const int j1 = 8 * g + 2 * wid + h;  // octave o = g for all 8 paths
    const int M1 = (g < 3) ? (1024 >> g) : 128;
    const float xi = 0.4f * exp2f(-(float)k);
    const int p = 4 * k * (k - 1) + j1;
    kC_dual(A + wid * 256 + h * 128, base + u1h_off(j1),
            out + ((size_t)b * 440 + 80 + p) * 6 + c, M1, M1 / 128, xi, ll);
  }
}

extern "C" void kernel_launch(void* const* d_in, const int* in_sizes, int n_in,
                              void* d_out, int out_size, void* d_ws, size_t ws_size,
                              hipStream_t stream) {
  (void)in_sizes; (void)n_in; (void)out_size; (void)ws_size;
  const float* x = (const float*)d_in[0];  // [8, 2048, 6] fp32
  float* out = (float*)d_out;              // [8, 440, 6] fp32
  float2* U1h = (float2*)d_ws;                                       // 8.1 MB
  float2* xh = (float2*)((char*)d_ws + (size_t)48 * U1H_STRIDE * sizeof(float2));
  kA<<<dim3(48), dim3(NTH), 0, stream>>>(x, xh);
  kB_all<<<dim3(19 * 48), dim3(NTH), 0, stream>>>(xh, U1h, out);
  kC_all<<<dim3(58 * 48), dim3(NTH), 0, stream>>>(U1h, out);
}